// Round 8
// baseline (539.651 us; speedup 1.0000x reference)
//
#include <hip/hip_runtime.h>
#include <math.h>

// predicted/target: (B,T,H,W,1) fp32
#define BB 8
#define TT 16
#define HH 256
#define WW 256
#define NPX (TT * HH * WW)      // 1,048,576 px per sample
#define CROWS 32                // output rows per ssim block
#define NROWS (CROWS + 10)      // 42 staged rows per block
#define CCOLS 64                // output cols per ssim block (one wave)
#define SW (CCOLS + 10)         // 74 staged cols
#define NSLOT 8                 // LDS row-ring slots
#define NBLK (BB * TT * (HH / CROWS) * (WW / CCOLS)) // 4096 one-wave blocks

// ws float layout (per-block partials from k_reduce; 512 = 8 samples x 64 chunks)
#define P_MINP 0
#define P_MAXP 512
#define P_MINT 1024
#define P_MAXT 1536
#define P_SUMT 2048
#define WS_SL  2560   // 64 accumulation slots (spread atomic contention)

typedef float v2f __attribute__((ext_vector_type(2)));

// Gaussian taps (exp(-(i-5)^2/4.5), normalized) as literals.
#define G0 0.0010283776f
#define G1 0.0075987582f
#define G2 0.0360008014f
#define G3 0.1093606427f
#define G4 0.2130055745f
#define G5 0.2660117857f
#define GA_(k) ((k) == 0 || (k) == 10 ? G0 : (k) == 1 || (k) == 9 ? G1 \
              : (k) == 2 || (k) == 8 ? G2 : (k) == 3 || (k) == 7 ? G3 \
              : (k) == 4 || (k) == 6 ? G4 : G5)

// Per-sample min/max of pred & targ + sum(targ), one partial per block.
__global__ __launch_bounds__(256) void k_reduce(const float* __restrict__ p,
                                                const float* __restrict__ t,
                                                float* __restrict__ wsf) {
  const int b = blockIdx.x >> 6;
  const size_t base = (size_t)b * NPX + (size_t)(blockIdx.x & 63) * (NPX / 64);
  const int tid = threadIdx.x;
  if (blockIdx.x == 0 && tid < 64) wsf[WS_SL + tid] = 0.f;

  float mnp = 3.4e38f, mxp = -3.4e38f, mnt = 3.4e38f, mxt = -3.4e38f, st = 0.f;
  const float4* p4 = (const float4*)(p + base);
  const float4* t4 = (const float4*)(t + base);
#pragma unroll 4
  for (int it = 0; it < 16; ++it) {
    float4 a = p4[it * 256 + tid];
    float4 c = t4[it * 256 + tid];
    mnp = fminf(mnp, fminf(fminf(a.x, a.y), fminf(a.z, a.w)));
    mxp = fmaxf(mxp, fmaxf(fmaxf(a.x, a.y), fmaxf(a.z, a.w)));
    mnt = fminf(mnt, fminf(fminf(c.x, c.y), fminf(c.z, c.w)));
    mxt = fmaxf(mxt, fmaxf(fmaxf(c.x, c.y), fmaxf(c.z, c.w)));
    st += c.x + c.y + c.z + c.w;
  }
  for (int off = 32; off > 0; off >>= 1) {
    mnp = fminf(mnp, __shfl_down(mnp, off));
    mxp = fmaxf(mxp, __shfl_down(mxp, off));
    mnt = fminf(mnt, __shfl_down(mnt, off));
    mxt = fmaxf(mxt, __shfl_down(mxt, off));
    st += __shfl_down(st, off);
  }
  __shared__ float s_mnp[4], s_mxp[4], s_mnt[4], s_mxt[4], s_st[4];
  int wave = tid >> 6, lane = tid & 63;
  if (lane == 0) {
    s_mnp[wave] = mnp; s_mxp[wave] = mxp;
    s_mnt[wave] = mnt; s_mxt[wave] = mxt; s_st[wave] = st;
  }
  __syncthreads();
  if (tid == 0) {
    for (int w = 1; w < 4; ++w) {
      mnp = fminf(mnp, s_mnp[w]); mxp = fmaxf(mxp, s_mxp[w]);
      mnt = fminf(mnt, s_mnt[w]); mxt = fmaxf(mxt, s_mxt[w]);
      st += s_st[w];
    }
    wsf[P_MINP + blockIdx.x] = mnp;
    wsf[P_MAXP + blockIdx.x] = mxp;
    wsf[P_MINT + blockIdx.x] = mnt;
    wsf[P_MAXT + blockIdx.x] = mxt;
    wsf[P_SUMT + blockIdx.x] = st;
  }
}

// --- Single-wave pipeline. No __syncthreads anywhere: one wave per block,
// DS ops execute in program order within a wave, so LDS write->read is safe;
// wave_barrier() (zero runtime cost) + sched_barrier(0) at phase boundaries
// stop the compiler from reordering cross-lane LDS accesses. This removes
// the s_waitcnt vmcnt(0)+s_barrier drain that pinned r4/r7 at 47.8 us.
// All row indices literal -> ring slot (%11) and LDS slot (&7) compile-time.

#define LOADR(R) do { constexpr int r_ = (R); if constexpr (r_ < NROWS) {     \
    const int yc_ = min(max(ystart + r_, 0), HH - 1);                          \
    const size_t ro_ = (size_t)yc_ * WW;                                       \
    tpre[r_ & 3] = tptr[ro_ + xm];                                             \
    ppre[r_ & 3] = pptr[ro_ + xm];                                             \
    if (x < 10) {                                                              \
      tpre2[r_ & 3] = tptr[ro_ + xh];                                          \
      ppre2[r_ & 3] = pptr[ro_ + xh];                                          \
    }                                                                          \
  } } while (0)

#define WRITER(R) do { constexpr int r_ = (R); if constexpr (r_ < NROWS) {     \
    const bool rin_ = (unsigned)(ystart + r_) < (unsigned)HH;                  \
    v2f nv_;                                                                   \
    nv_.x = (rin_ && cmin) ? fmaf(tpre[r_ & 3], ts, tb) : 0.f;                 \
    nv_.y = (rin_ && cmin) ? fmaf(ppre[r_ & 3], ps, pb) : 0.f;                 \
    srow[r_ & (NSLOT - 1)][x] = nv_;                                           \
    if (x < 10) {                                                              \
      v2f nh_;                                                                 \
      nh_.x = (rin_ && chin) ? fmaf(tpre2[r_ & 3], ts, tb) : 0.f;              \
      nh_.y = (rin_ && chin) ? fmaf(ppre2[r_ & 3], ps, pb) : 0.f;              \
      srow[r_ & (NSLOT - 1)][CCOLS + x] = nh_;                                 \
    }                                                                          \
  } } while (0)

#define CSTEP(R) do { constexpr int r_ = (R); if constexpr (r_ < NROWS) {      \
    constexpr int slot_ = r_ % 11;                                             \
    v2f hmu = {0.f, 0.f}, hsq = {0.f, 0.f};                                    \
    float htp = 0.f;                                                           \
    _Pragma("unroll")                                                          \
    for (int k = 0; k < 11; ++k) {                                             \
      v2f v = srow[r_ & (NSLOT - 1)][x + k];                                   \
      v2f g2 = {GA_(k), GA_(k)};                                               \
      v2f w = g2 * v;                                                          \
      hmu = hmu + w;                                                           \
      hsq = __builtin_elementwise_fma(w, v, hsq);                              \
      htp = fmaf(w.x, v.y, htp);                                               \
    }                                                                          \
    r_mu[slot_] = hmu; r_sq[slot_] = hsq; r_tp[slot_] = htp;                   \
    if constexpr (r_ >= 10) {                                                  \
      v2f vmu = {0.f, 0.f}, vsq = {0.f, 0.f};                                  \
      float vtp = 0.f;                                                         \
      _Pragma("unroll")                                                        \
      for (int k = 0; k < 11; ++k) {                                           \
        const int s = (r_ + 1 + k) % 11;                                       \
        v2f g2 = {GA_(k), GA_(k)};                                             \
        vmu = __builtin_elementwise_fma(g2, r_mu[s], vmu);                     \
        vsq = __builtin_elementwise_fma(g2, r_sq[s], vsq);                     \
        vtp = fmaf(GA_(k), r_tp[s], vtp);                                      \
      }                                                                        \
      float m1 = vmu.x, m2 = vmu.y;                                            \
      float mu11 = m1 * m1, mu22 = m2 * m2, m12 = m1 * m2;                     \
      float s1 = fmaxf(vsq.x - mu11, 1e-6f);                                   \
      float s2 = fmaxf(vsq.y - mu22, 1e-6f);                                   \
      float s12 = vtp - m12;                                                   \
      float root = sqrtf(s1 * s2);                                             \
      float num = fmaf(2.f, m12, C1) * fmaf(2.f, root, C2) * (s12 + C3);       \
      float den = (mu11 + mu22 + C1) * (s1 + s2 + C2) * (root + C3);           \
      acc = fmaf(num, __builtin_amdgcn_rcpf(den), acc);                        \
    }                                                                          \
  } } while (0)

#define PHASE(P) do {                                                          \
    LOADR(4*(P)+4); LOADR(4*(P)+5); LOADR(4*(P)+6); LOADR(4*(P)+7);            \
    CSTEP(4*(P)+0); CSTEP(4*(P)+1); CSTEP(4*(P)+2); CSTEP(4*(P)+3);            \
    WRITER(4*(P)+4); WRITER(4*(P)+5); WRITER(4*(P)+6); WRITER(4*(P)+7);        \
    __builtin_amdgcn_wave_barrier();                                           \
    __builtin_amdgcn_sched_barrier(0);                                         \
  } while (0)

__global__ __launch_bounds__(64, 4) void k_ssim(const float* __restrict__ pred,
                                                const float* __restrict__ targ,
                                                float* __restrict__ wsf) {
  const int cchunk = blockIdx.x & 3;          // cols fastest -> L2 locality
  const int rchunk = (blockIdx.x >> 2) & 7;
  const int img = blockIdx.x >> 5;            // 0..127
  const int b = img >> 4;                     // sample
  const int x = threadIdx.x;                  // 0..63, one col each
  const int y0 = rchunk * CROWS;
  const int cb = cchunk * CCOLS;
  const float* tptr = targ + (size_t)img * (HH * WW);
  const float* pptr = pred + (size_t)img * (HH * WW);

  // Column addresses (fixed per thread): main staged col = cb+x-5,
  // halo staged col (lanes 0..9) = cb+59+x.
  const int xm = min(max(cb + x - 5, 0), WW - 1);
  const bool cmin = (cb + x - 5) >= 0;        // upper bound can't fail
  const int xh = min(cb + 59 + x, WW - 1);
  const bool chin = (cb + 59 + x) < WW;

  // Preamble: reduce this sample's 64 partials -> norm params + valid.
  // Single wave: shuffle-reduce then broadcast from lane 0 — no LDS.
  float mnp = wsf[P_MINP + b * 64 + x];
  float mxp = wsf[P_MAXP + b * 64 + x];
  float mnt = wsf[P_MINT + b * 64 + x];
  float mxt = wsf[P_MAXT + b * 64 + x];
  float st  = wsf[P_SUMT + b * 64 + x];
  for (int off = 32; off > 0; off >>= 1) {
    mnp = fminf(mnp, __shfl_down(mnp, off));
    mxp = fmaxf(mxp, __shfl_down(mxp, off));
    mnt = fminf(mnt, __shfl_down(mnt, off));
    mxt = fmaxf(mxt, __shfl_down(mxt, off));
    st += __shfl_down(st, off);
  }
  mnp = __shfl(mnp, 0); mxp = __shfl(mxp, 0);
  mnt = __shfl(mnt, 0); mxt = __shfl(mxt, 0);
  st  = __shfl(st, 0);
  const float ps = 1.f / fmaxf(mxp - mnp, 1e-6f);
  const float pb = -mnp * ps;
  const float ts = 1.f / fmaxf(mxt - mnt, 1e-6f);
  const float tb = -mnt * ts;
  const float valid = (st != 0.f) ? 1.f : 0.f;

  // LDS row ring: NSLOT rows of SW staged (t,p) v2f values.
  __shared__ v2f srow[NSLOT][SW];

  // Register ring: h-conv results for 11 rows; constant indices -> VGPRs.
  v2f r_mu[11], r_sq[11];
  float r_tp[11];
  float acc = 0.f;
  const int ystart = y0 - 5;  // staged row r is image row ystart+r
  const float C1 = 1e-4f, C2 = 9e-4f, C3 = 4.5e-4f;

  float tpre[4], ppre[4], tpre2[4], ppre2[4];

  // Prologue: stage rows 0..3
  LOADR(0); LOADR(1); LOADR(2); LOADR(3);
  WRITER(0); WRITER(1); WRITER(2); WRITER(3);
  __builtin_amdgcn_wave_barrier();
  __builtin_amdgcn_sched_barrier(0);

  PHASE(0); PHASE(1); PHASE(2); PHASE(3); PHASE(4);
  PHASE(5); PHASE(6); PHASE(7); PHASE(8); PHASE(9);
  CSTEP(40); CSTEP(41);  // tail (rows written during PHASE(9))

  // Wave reduction + valid-weighted accumulate into one of 64 slots.
  for (int off = 32; off > 0; off >>= 1) acc += __shfl_down(acc, off);
  if (x == 0) atomicAdd(&wsf[WS_SL + (blockIdx.x & 63)], acc * valid);
}

__global__ void k_loss(const float* __restrict__ wsf, float* __restrict__ out) {
  const int c = threadIdx.x;  // 64 threads
  float sums[8];
#pragma unroll
  for (int b = 0; b < 8; ++b) sums[b] = wsf[P_SUMT + b * 64 + c];
  float S = wsf[WS_SL + c];
  for (int off = 32; off > 0; off >>= 1) {
#pragma unroll
    for (int b = 0; b < 8; ++b) sums[b] += __shfl_down(sums[b], off);
    S += __shfl_down(S, off);
  }
  if (c == 0) {
    float sv = 0.f;
#pragma unroll
    for (int b = 0; b < 8; ++b) sv += (sums[b] != 0.f) ? 1.f : 0.f;
    out[0] = (sv - S * (1.f / (float)NPX)) / fmaxf(sv, 1.f);
  }
}

extern "C" void kernel_launch(void* const* d_in, const int* in_sizes, int n_in,
                              void* d_out, int out_size, void* d_ws, size_t ws_size,
                              hipStream_t stream) {
  const float* pred = (const float*)d_in[0];
  const float* targ = (const float*)d_in[1];
  float* wsf = (float*)d_ws;
  float* out = (float*)d_out;

  hipLaunchKernelGGL(k_reduce, dim3(512), dim3(256), 0, stream, pred, targ, wsf);
  hipLaunchKernelGGL(k_ssim, dim3(NBLK), dim3(64), 0, stream, pred, targ, wsf);
  hipLaunchKernelGGL(k_loss, dim3(1), dim3(64), 0, stream, wsf, out);
}

// Round 9
// 352.139 us; speedup vs baseline: 1.5325x; 1.5325x over previous
//
#include <hip/hip_runtime.h>
#include <math.h>

// predicted/target: (B,T,H,W,1) fp32
#define BB 8
#define TT 16
#define HH 256
#define WW 256
#define NPX (TT * HH * WW)      // 1,048,576 px per sample
#define CROWS 32                // output rows per ssim block
#define NROWS (CROWS + 10)      // 42 staged rows
#define CCOLS 128               // output cols per ssim block
#define SW (CCOLS + 10)         // 138 staged cols
#define NSLOT 8                 // LDS row-ring slots
#define NBLK (BB * TT * (HH / CROWS) * (WW / CCOLS)) // 2048 blocks

// ws float layout (per-block partials from k_reduce; 512 = 8 samples x 64 chunks)
#define P_MINP 0
#define P_MAXP 512
#define P_MINT 1024
#define P_MAXT 1536
#define P_SUMT 2048
#define WS_SL  2560   // 64 accumulation slots (spread atomic contention)

typedef float v2f __attribute__((ext_vector_type(2)));

// Gaussian taps (exp(-(i-5)^2/4.5), normalized) as literals.
#define G0 0.0010283776f
#define G1 0.0075987582f
#define G2 0.0360008014f
#define G3 0.1093606427f
#define G4 0.2130055745f
#define G5 0.2660117857f
#define GA_(k) ((k) == 0 || (k) == 10 ? G0 : (k) == 1 || (k) == 9 ? G1 \
              : (k) == 2 || (k) == 8 ? G2 : (k) == 3 || (k) == 7 ? G3 \
              : (k) == 4 || (k) == 6 ? G4 : G5)

// Per-sample min/max of pred & targ + sum(targ), one partial per block.
__global__ __launch_bounds__(256) void k_reduce(const float* __restrict__ p,
                                                const float* __restrict__ t,
                                                float* __restrict__ wsf) {
  const int b = blockIdx.x >> 6;
  const size_t base = (size_t)b * NPX + (size_t)(blockIdx.x & 63) * (NPX / 64);
  const int tid = threadIdx.x;
  if (blockIdx.x == 0 && tid < 64) wsf[WS_SL + tid] = 0.f;

  float mnp = 3.4e38f, mxp = -3.4e38f, mnt = 3.4e38f, mxt = -3.4e38f, st = 0.f;
  const float4* p4 = (const float4*)(p + base);
  const float4* t4 = (const float4*)(t + base);
#pragma unroll 4
  for (int it = 0; it < 16; ++it) {
    float4 a = p4[it * 256 + tid];
    float4 c = t4[it * 256 + tid];
    mnp = fminf(mnp, fminf(fminf(a.x, a.y), fminf(a.z, a.w)));
    mxp = fmaxf(mxp, fmaxf(fmaxf(a.x, a.y), fmaxf(a.z, a.w)));
    mnt = fminf(mnt, fminf(fminf(c.x, c.y), fminf(c.z, c.w)));
    mxt = fmaxf(mxt, fmaxf(fmaxf(c.x, c.y), fmaxf(c.z, c.w)));
    st += c.x + c.y + c.z + c.w;
  }
  for (int off = 32; off > 0; off >>= 1) {
    mnp = fminf(mnp, __shfl_down(mnp, off));
    mxp = fmaxf(mxp, __shfl_down(mxp, off));
    mnt = fminf(mnt, __shfl_down(mnt, off));
    mxt = fmaxf(mxt, __shfl_down(mxt, off));
    st += __shfl_down(st, off);
  }
  __shared__ float s_mnp[4], s_mxp[4], s_mnt[4], s_mxt[4], s_st[4];
  int wave = tid >> 6, lane = tid & 63;
  if (lane == 0) {
    s_mnp[wave] = mnp; s_mxp[wave] = mxp;
    s_mnt[wave] = mnt; s_mxt[wave] = mxt; s_st[wave] = st;
  }
  __syncthreads();
  if (tid == 0) {
    for (int w = 1; w < 4; ++w) {
      mnp = fminf(mnp, s_mnp[w]); mxp = fmaxf(mxp, s_mxp[w]);
      mnt = fminf(mnt, s_mnt[w]); mxt = fmaxf(mxt, s_mxt[w]);
      st += s_st[w];
    }
    wsf[P_MINP + blockIdx.x] = mnp;
    wsf[P_MAXP + blockIdx.x] = mxp;
    wsf[P_MINT + blockIdx.x] = mnt;
    wsf[P_MAXT + blockIdx.x] = mxt;
    wsf[P_SUMT + blockIdx.x] = st;
  }
}

// --- Phase-grouped pipeline (r7 machinery) on 2-wave, 128-col blocks.
// All loads UNIFORM (halo cols loaded by every lane, clamped address, result
// masked at write) — no divergently-written register arrays (r8 spill cause).
// Row indices literal -> ring slot (%11) and LDS slot (&7) compile-time.

#define LOADR(R) do { constexpr int r_ = (R); if constexpr (r_ < NROWS) {      \
    const int yc_ = min(max(ystart + r_, 0), HH - 1);                          \
    const size_t ro_ = (size_t)yc_ * WW;                                       \
    tpre[r_ & 3] = tptr[ro_ + xm];                                             \
    ppre[r_ & 3] = pptr[ro_ + xm];                                             \
    thpre[r_ & 3] = tptr[ro_ + xh];                                            \
    phpre[r_ & 3] = pptr[ro_ + xh];                                            \
  } } while (0)

#define WRITER(R) do { constexpr int r_ = (R); if constexpr (r_ < NROWS) {     \
    const bool rin_ = (unsigned)(ystart + r_) < (unsigned)HH;                  \
    v2f nv_;                                                                   \
    nv_.x = (rin_ && cmin) ? fmaf(tpre[r_ & 3], ts, tb) : 0.f;                 \
    nv_.y = (rin_ && cmin) ? fmaf(ppre[r_ & 3], ps, pb) : 0.f;                 \
    srow[r_ & (NSLOT - 1)][x] = nv_;                                           \
    if (x < 10) {                                                              \
      v2f nh_;                                                                 \
      nh_.x = (rin_ && chin) ? fmaf(thpre[r_ & 3], ts, tb) : 0.f;              \
      nh_.y = (rin_ && chin) ? fmaf(phpre[r_ & 3], ps, pb) : 0.f;              \
      srow[r_ & (NSLOT - 1)][CCOLS + x] = nh_;                                 \
    }                                                                          \
  } } while (0)

#define CSTEP(R) do { constexpr int r_ = (R); if constexpr (r_ < NROWS) {      \
    constexpr int slot_ = r_ % 11;                                             \
    v2f hmu = {0.f, 0.f}, hsq = {0.f, 0.f};                                    \
    float htp = 0.f;                                                           \
    _Pragma("unroll")                                                          \
    for (int k = 0; k < 11; ++k) {                                             \
      v2f v = srow[r_ & (NSLOT - 1)][x + k];                                   \
      v2f g2 = {GA_(k), GA_(k)};                                               \
      v2f w = g2 * v;                                                          \
      hmu = hmu + w;                                                           \
      hsq = __builtin_elementwise_fma(w, v, hsq);                              \
      htp = fmaf(w.x, v.y, htp);                                               \
    }                                                                          \
    r_mu[slot_] = hmu; r_sq[slot_] = hsq; r_tp[slot_] = htp;                   \
    if constexpr (r_ >= 10) {                                                  \
      v2f vmu = {0.f, 0.f}, vsq = {0.f, 0.f};                                  \
      float vtp = 0.f;                                                         \
      _Pragma("unroll")                                                        \
      for (int k = 0; k < 11; ++k) {                                           \
        const int s = (r_ + 1 + k) % 11;                                       \
        v2f g2 = {GA_(k), GA_(k)};                                             \
        vmu = __builtin_elementwise_fma(g2, r_mu[s], vmu);                     \
        vsq = __builtin_elementwise_fma(g2, r_sq[s], vsq);                     \
        vtp = fmaf(GA_(k), r_tp[s], vtp);                                      \
      }                                                                        \
      float m1 = vmu.x, m2 = vmu.y;                                            \
      float mu11 = m1 * m1, mu22 = m2 * m2, m12 = m1 * m2;                     \
      float s1 = fmaxf(vsq.x - mu11, 1e-6f);                                   \
      float s2 = fmaxf(vsq.y - mu22, 1e-6f);                                   \
      float s12 = vtp - m12;                                                   \
      float root = sqrtf(s1 * s2);                                             \
      float num = fmaf(2.f, m12, C1) * fmaf(2.f, root, C2) * (s12 + C3);       \
      float den = (mu11 + mu22 + C1) * (s1 + s2 + C2) * (root + C3);           \
      acc = fmaf(num, __builtin_amdgcn_rcpf(den), acc);                        \
    }                                                                          \
  } } while (0)

#define PHASE(P) do {                                                          \
    LOADR(4*(P)+4); LOADR(4*(P)+5); LOADR(4*(P)+6); LOADR(4*(P)+7);            \
    CSTEP(4*(P)+0); CSTEP(4*(P)+1); CSTEP(4*(P)+2); CSTEP(4*(P)+3);            \
    WRITER(4*(P)+4); WRITER(4*(P)+5); WRITER(4*(P)+6); WRITER(4*(P)+7);        \
    __syncthreads();                                                           \
    __builtin_amdgcn_sched_barrier(0);                                         \
  } while (0)

__global__ __launch_bounds__(128, 4) void k_ssim(const float* __restrict__ pred,
                                                 const float* __restrict__ targ,
                                                 float* __restrict__ wsf) {
  const int cchunk = blockIdx.x & 1;
  const int rchunk = (blockIdx.x >> 1) & 7;
  const int img = blockIdx.x >> 4;            // 0..127
  const int b = img >> 4;                     // sample
  const int x = threadIdx.x;                  // 0..127, one output col each
  const int y0 = rchunk * CROWS;
  const int cb = cchunk * CCOLS;
  const float* tptr = targ + (size_t)img * (HH * WW);
  const float* pptr = pred + (size_t)img * (HH * WW);

  // Column addresses (fixed per thread): main staged col cb+x-5; halo staged
  // col cb+123+x (meaningful for lanes 0..9, loaded by all lanes, clamped).
  const int xm = min(max(cb + x - 5, 0), WW - 1);
  const bool cmin = (cb + x - 5) >= 0;   // upper bound can't fail (<=250)
  const int xh = min(cb + 123 + x, WW - 1);
  const bool chin = (cb + 123 + x) < WW;

  // Preamble: reduce this sample's 64 partials -> norm params + valid (wave 0)
  __shared__ float sprm[5];  // ps, pb, ts, tb, valid
  if (x < 64) {
    float mnp = wsf[P_MINP + b * 64 + x];
    float mxp = wsf[P_MAXP + b * 64 + x];
    float mnt = wsf[P_MINT + b * 64 + x];
    float mxt = wsf[P_MAXT + b * 64 + x];
    float st  = wsf[P_SUMT + b * 64 + x];
    for (int off = 32; off > 0; off >>= 1) {
      mnp = fminf(mnp, __shfl_down(mnp, off));
      mxp = fmaxf(mxp, __shfl_down(mxp, off));
      mnt = fminf(mnt, __shfl_down(mnt, off));
      mxt = fmaxf(mxt, __shfl_down(mxt, off));
      st += __shfl_down(st, off);
    }
    if (x == 0) {
      float psv = 1.f / fmaxf(mxp - mnp, 1e-6f);
      float tsv = 1.f / fmaxf(mxt - mnt, 1e-6f);
      sprm[0] = psv; sprm[1] = -mnp * psv;
      sprm[2] = tsv; sprm[3] = -mnt * tsv;
      sprm[4] = (st != 0.f) ? 1.f : 0.f;
    }
  }

  // LDS row ring: NSLOT rows of SW staged (t,p) v2f values.
  __shared__ v2f srow[NSLOT][SW];
  __syncthreads();
  const float ps = sprm[0], pb = sprm[1], ts = sprm[2], tb = sprm[3];
  const float valid = sprm[4];

  // Register ring: h-conv results for 11 rows; constant indices -> VGPRs.
  v2f r_mu[11], r_sq[11];
  float r_tp[11];
  float acc = 0.f;
  const int ystart = y0 - 5;  // staged row r is image row ystart+r
  const float C1 = 1e-4f, C2 = 9e-4f, C3 = 4.5e-4f;

  float tpre[4], ppre[4], thpre[4], phpre[4];

  // Prologue: stage rows 0..3
  LOADR(0); LOADR(1); LOADR(2); LOADR(3);
  WRITER(0); WRITER(1); WRITER(2); WRITER(3);
  __syncthreads();
  __builtin_amdgcn_sched_barrier(0);

  PHASE(0); PHASE(1); PHASE(2); PHASE(3); PHASE(4);
  PHASE(5); PHASE(6); PHASE(7); PHASE(8); PHASE(9);
  CSTEP(40); CSTEP(41);  // tail (rows written during PHASE(9))

  // Block (2-wave) reduction + valid-weighted accumulate into 1 of 64 slots.
  for (int off = 32; off > 0; off >>= 1) acc += __shfl_down(acc, off);
  __shared__ float sred[2];
  if ((x & 63) == 0) sred[x >> 6] = acc;
  __syncthreads();
  if (x == 0)
    atomicAdd(&wsf[WS_SL + (blockIdx.x & 63)], (sred[0] + sred[1]) * valid);
}

__global__ void k_loss(const float* __restrict__ wsf, float* __restrict__ out) {
  const int c = threadIdx.x;  // 64 threads
  float sums[8];
#pragma unroll
  for (int b = 0; b < 8; ++b) sums[b] = wsf[P_SUMT + b * 64 + c];
  float S = wsf[WS_SL + c];
  for (int off = 32; off > 0; off >>= 1) {
#pragma unroll
    for (int b = 0; b < 8; ++b) sums[b] += __shfl_down(sums[b], off);
    S += __shfl_down(S, off);
  }
  if (c == 0) {
    float sv = 0.f;
#pragma unroll
    for (int b = 0; b < 8; ++b) sv += (sums[b] != 0.f) ? 1.f : 0.f;
    out[0] = (sv - S * (1.f / (float)NPX)) / fmaxf(sv, 1.f);
  }
}

extern "C" void kernel_launch(void* const* d_in, const int* in_sizes, int n_in,
                              void* d_out, int out_size, void* d_ws, size_t ws_size,
                              hipStream_t stream) {
  const float* pred = (const float*)d_in[0];
  const float* targ = (const float*)d_in[1];
  float* wsf = (float*)d_ws;
  float* out = (float*)d_out;

  hipLaunchKernelGGL(k_reduce, dim3(512), dim3(256), 0, stream, pred, targ, wsf);
  hipLaunchKernelGGL(k_ssim, dim3(NBLK), dim3(128), 0, stream, pred, targ, wsf);
  hipLaunchKernelGGL(k_loss, dim3(1), dim3(64), 0, stream, wsf, out);
}